// Round 4
// baseline (1434.996 us; speedup 1.0000x reference)
//
#include <hip/hip_runtime.h>

#define N_NODES 50000
#define IN_DIM  3000
#define HID     512
#define LAT     30
#define N_EDGES 800000
#define M_PAD   50048   // 391*128
#define K1_PAD  3008    // 94*32
#define N4_PAD  3072    // 24*128

typedef __bf16 bf16;
typedef unsigned int uint;
typedef __attribute__((ext_vector_type(4))) float f32x4;
typedef __attribute__((ext_vector_type(8))) bf16 bf16x8;

__device__ __forceinline__ float bf2f(bf16 b){ return (float)b; }

__device__ __forceinline__ void gl16(const void* g, void* l){
  __builtin_amdgcn_global_load_lds(
      (const __attribute__((address_space(1))) void*)g,
      (__attribute__((address_space(3))) void*)l, 16, 0, 0);
}

// bijective XCD-aware swizzle (m204)
__device__ __forceinline__ int xcd_swz(int orig, int nwg){
  int q = nwg >> 3, r = nwg & 7;
  int xcd = orig & 7, lid = orig >> 3;
  return (xcd < r ? xcd*(q+1) : r*(q+1) + (xcd-r)*q) + lid;
}

__device__ __forceinline__ bf16x8 cvt8(float4 a, float4 b){
  bf16x8 r;
  r[0]=(bf16)a.x; r[1]=(bf16)a.y; r[2]=(bf16)a.z; r[3]=(bf16)a.w;
  r[4]=(bf16)b.x; r[5]=(bf16)b.y; r[6]=(bf16)b.z; r[7]=(bf16)b.w;
  return r;
}

// ---------------- weight prep ----------------
__global__ void k_w1t(const float* __restrict__ W1, bf16* __restrict__ W1T){
  int k = blockIdx.x*256 + threadIdx.x;
  int n = blockIdx.y;
  if (k >= K1_PAD) return;
  float v = (k < IN_DIM) ? W1[(long)k*HID + n] : 0.f;
  W1T[(long)n*K1_PAD + k] = (bf16)v;
}
__global__ void k_w1p(const float* __restrict__ W1, bf16* __restrict__ W1P){
  int k = blockIdx.x*256 + threadIdx.x;
  int n = blockIdx.y;
  if (k >= HID) return;
  float v = (n < IN_DIM) ? W1[(long)n*HID + k] : 0.f;
  W1P[(long)n*HID + k] = (bf16)v;
}
__global__ void k_w2t(const float* __restrict__ W2, bf16* __restrict__ W2T){
  int k = blockIdx.x*256 + threadIdx.x;
  int n = blockIdx.y;
  if (k >= HID) return;
  float v = (n < LAT) ? W2[(long)k*LAT + n] : 0.f;
  W2T[(long)n*HID + k] = (bf16)v;
}
__global__ void k_w2p(const float* __restrict__ W2, bf16* __restrict__ W2P){
  int t = blockIdx.x*256 + threadIdx.x;
  if (t >= HID*32) return;
  int n = t >> 5, k = t & 31;
  W2P[t] = (bf16)((k < LAT) ? W2[(long)n*LAT + k] : 0.f);
}

// ---- gemm1: h1 = (fp32 x) @ W1T^T, A direct-to-reg (2-deep prefetch) ----
// A fragments loaded per-lane from global (coalesced: 16 rows x 64B lines),
// cvt fp32->bf16 at consume; B dbuf via global_load_lds; counted vmcnt(10),
// raw barriers -- loads stay in flight across barriers (no vmcnt(0) drain).

#define STAGE_M(kc, P0,P1,P2,P3,P4,P5,P6,P7, LB) do{                            \
  int k_ = (kc)*32 + klane;                                                     \
  int ka_ = min(k_, IN_DIM-4), kb_ = min(k_+4, IN_DIM-4);                       \
  P0 = *(const float4*)(X + off0 + ka_); P1 = *(const float4*)(X + off0 + kb_); \
  P2 = *(const float4*)(X + off1 + ka_); P3 = *(const float4*)(X + off1 + kb_); \
  P4 = *(const float4*)(X + off2 + ka_); P5 = *(const float4*)(X + off2 + kb_); \
  P6 = *(const float4*)(X + off3 + ka_); P7 = *(const float4*)(X + off3 + kb_); \
  gl16(gB + (long)(kc)*64, LB);                                                 \
  gl16(gB + (long)(kc)*64 + bstep, LB + 64*64);                                 \
}while(0)

#define COMPUTE_M(P0,P1,P2,P3,P4,P5,P6,P7, LBASE) do{                           \
  asm volatile("s_waitcnt vmcnt(10)" ::: "memory");                             \
  __builtin_amdgcn_s_barrier();                                                 \
  bf16x8 af0 = cvt8(P0,P1), af1 = cvt8(P2,P3);                                  \
  bf16x8 af2 = cvt8(P4,P5), af3 = cvt8(P6,P7);                                  \
  const bf16* Lb_ = (LBASE);                                                    \
  bf16x8 bf0 = *(const bf16x8*)&Lb_[(wn +  0 + r_l)*32 + klane];                \
  bf16x8 bf1 = *(const bf16x8*)&Lb_[(wn + 16 + r_l)*32 + klane];                \
  bf16x8 bf2 = *(const bf16x8*)&Lb_[(wn + 32 + r_l)*32 + klane];                \
  bf16x8 bf3 = *(const bf16x8*)&Lb_[(wn + 48 + r_l)*32 + klane];                \
  acc[0][0] = __builtin_amdgcn_mfma_f32_16x16x32_bf16(af0, bf0, acc[0][0],0,0,0); \
  acc[0][1] = __builtin_amdgcn_mfma_f32_16x16x32_bf16(af0, bf1, acc[0][1],0,0,0); \
  acc[0][2] = __builtin_amdgcn_mfma_f32_16x16x32_bf16(af0, bf2, acc[0][2],0,0,0); \
  acc[0][3] = __builtin_amdgcn_mfma_f32_16x16x32_bf16(af0, bf3, acc[0][3],0,0,0); \
  acc[1][0] = __builtin_amdgcn_mfma_f32_16x16x32_bf16(af1, bf0, acc[1][0],0,0,0); \
  acc[1][1] = __builtin_amdgcn_mfma_f32_16x16x32_bf16(af1, bf1, acc[1][1],0,0,0); \
  acc[1][2] = __builtin_amdgcn_mfma_f32_16x16x32_bf16(af1, bf2, acc[1][2],0,0,0); \
  acc[1][3] = __builtin_amdgcn_mfma_f32_16x16x32_bf16(af1, bf3, acc[1][3],0,0,0); \
  acc[2][0] = __builtin_amdgcn_mfma_f32_16x16x32_bf16(af2, bf0, acc[2][0],0,0,0); \
  acc[2][1] = __builtin_amdgcn_mfma_f32_16x16x32_bf16(af2, bf1, acc[2][1],0,0,0); \
  acc[2][2] = __builtin_amdgcn_mfma_f32_16x16x32_bf16(af2, bf2, acc[2][2],0,0,0); \
  acc[2][3] = __builtin_amdgcn_mfma_f32_16x16x32_bf16(af2, bf3, acc[2][3],0,0,0); \
  acc[3][0] = __builtin_amdgcn_mfma_f32_16x16x32_bf16(af3, bf0, acc[3][0],0,0,0); \
  acc[3][1] = __builtin_amdgcn_mfma_f32_16x16x32_bf16(af3, bf1, acc[3][1],0,0,0); \
  acc[3][2] = __builtin_amdgcn_mfma_f32_16x16x32_bf16(af3, bf2, acc[3][2],0,0,0); \
  acc[3][3] = __builtin_amdgcn_mfma_f32_16x16x32_bf16(af3, bf3, acc[3][3],0,0,0); \
  __builtin_amdgcn_s_barrier();                                                 \
}while(0)

__global__ __launch_bounds__(256, 2) void gemm_a32r(
    const float* __restrict__ X, const bf16* __restrict__ Bw, bf16* __restrict__ C)
{
  __shared__ bf16 Blds[2][128*32];
  const int NBX = HID/128;           // 4
  const int tid  = threadIdx.x;
  const int lane = tid & 63;
  const int w    = tid >> 6;
  const int wm   = (w >> 1) * 64, wn = (w & 1) * 64;
  const int wgid = xcd_swz(blockIdx.x, gridDim.x);
  const int col0 = (wgid % NBX) * 128, row0 = (wgid / NBX) * 128;

  f32x4 acc[4][4];
  #pragma unroll
  for (int mi=0;mi<4;mi++)
    #pragma unroll
    for (int ni=0;ni<4;ni++)
      acc[mi][ni] = (f32x4){0.f,0.f,0.f,0.f};

  const int klane = (lane >> 4) * 8;
  const int r_l   = lane & 15;
  // A row offsets (element units; clamped rows only feed unwritten C rows)
  const int off0 = min(row0 + wm +  0 + r_l, N_NODES-1) * IN_DIM;
  const int off1 = min(row0 + wm + 16 + r_l, N_NODES-1) * IN_DIM;
  const int off2 = min(row0 + wm + 32 + r_l, N_NODES-1) * IN_DIM;
  const int off3 = min(row0 + wm + 48 + r_l, N_NODES-1) * IN_DIM;

  // B staging (linear lane->16B, glds-compatible)
  const int sr = tid >> 2;
  const int sc = (tid & 3) * 16;
  const char* gB = (const char*)(Bw + (long)(col0 + sr) * K1_PAD) + sc;
  const long bstep = (long)64 * K1_PAD * 2;
  char* lB0w = (char*)&Blds[0][0] + sr*64 + sc;
  char* lB1w = (char*)&Blds[1][0] + sr*64 + sc;

  float4 a00,a01,a02,a03,a04,a05,a06,a07;
  float4 a10,a11,a12,a13,a14,a15,a16,a17;

  STAGE_M(0, a00,a01,a02,a03,a04,a05,a06,a07, lB0w);
  STAGE_M(1, a10,a11,a12,a13,a14,a15,a16,a17, lB1w);

  for (int kb = 0; kb < 94; kb += 2){
    COMPUTE_M(a00,a01,a02,a03,a04,a05,a06,a07, &Blds[0][0]);
    STAGE_M(min(kb+2,93), a00,a01,a02,a03,a04,a05,a06,a07, lB0w);
    COMPUTE_M(a10,a11,a12,a13,a14,a15,a16,a17, &Blds[1][0]);
    STAGE_M(min(kb+3,93), a10,a11,a12,a13,a14,a15,a16,a17, lB1w);
  }

  const int crb  = (lane >> 4) * 4;
  const int ccol = lane & 15;
  #pragma unroll
  for (int mi=0;mi<4;mi++){
    #pragma unroll
    for (int v=0;v<4;v++){
      int r = row0 + wm + mi*16 + crb + v;
      if (r >= N_NODES) continue;
      #pragma unroll
      for (int ni=0;ni<4;ni++){
        int cc = col0 + wn + ni*16 + ccol;
        C[(long)r*HID + cc] = (bf16)acc[mi][ni][v];
      }
    }
  }
}

// ---------------- GEMM (m97 structure): C = A * B^T, flat grid + swizzle ----
template<bool C_F32, bool ELU>
__global__ __launch_bounds__(256) void gemm_glds(
    const bf16* __restrict__ A, const bf16* __restrict__ B, void* __restrict__ Cp,
    int lda, int ldb, int Ksteps, int Mvalid, int Nvalid, int ldc, int NBX)
{
  __shared__ bf16 Alds[128*32];
  __shared__ bf16 Blds[128*32];
  const int tid  = threadIdx.x;
  const int lane = tid & 63;
  const int w    = tid >> 6;
  const int wm   = (w >> 1) * 64, wn = (w & 1) * 64;
  const int wgid = xcd_swz(blockIdx.x, gridDim.x);
  const int col0 = (wgid % NBX) * 128, row0 = (wgid / NBX) * 128;

  f32x4 acc[4][4];
  #pragma unroll
  for (int mi=0;mi<4;mi++)
    #pragma unroll
    for (int ni=0;ni<4;ni++)
      acc[mi][ni] = (f32x4){0.f,0.f,0.f,0.f};

  const int sr = tid >> 2;
  const int sc = (tid & 3) * 16;

  const char* ga = (const char*)(A + (long)(row0 + sr) * lda) + sc;
  const char* gb = (const char*)(B + (long)(col0 + sr) * ldb) + sc;
  char* la = (char*)Alds + sr*64 + sc;
  char* lb = (char*)Blds + sr*64 + sc;
  const long astep = (long)64 * lda * 2;
  const long bstep = (long)64 * ldb * 2;

  for (int ks = 0; ks < Ksteps; ks++){
    const long ko = (long)ks * 64;
    gl16(ga + ko,         la);
    gl16(ga + ko + astep, la + 64*64);
    gl16(gb + ko,         lb);
    gl16(gb + ko + bstep, lb + 64*64);
    __syncthreads();

    bf16x8 af[4], bfr[4];
    #pragma unroll
    for (int mi=0;mi<4;mi++)
      af[mi] = *(const bf16x8*)&Alds[(wm + mi*16 + (lane & 15))*32 + (lane>>4)*8];
    #pragma unroll
    for (int ni=0;ni<4;ni++)
      bfr[ni] = *(const bf16x8*)&Blds[(wn + ni*16 + (lane & 15))*32 + (lane>>4)*8];
    #pragma unroll
    for (int mi=0;mi<4;mi++)
      #pragma unroll
      for (int ni=0;ni<4;ni++)
        acc[mi][ni] = __builtin_amdgcn_mfma_f32_16x16x32_bf16(af[mi], bfr[ni], acc[mi][ni], 0, 0, 0);
    __syncthreads();
  }

  const int crb  = (lane >> 4) * 4;
  const int ccol = lane & 15;
  #pragma unroll
  for (int mi=0;mi<4;mi++){
    #pragma unroll
    for (int v=0;v<4;v++){
      int r = row0 + wm + mi*16 + crb + v;
      if (r >= Mvalid) continue;
      #pragma unroll
      for (int ni=0;ni<4;ni++){
        int c = col0 + wn + ni*16 + ccol;
        if (c >= Nvalid) continue;
        float val = acc[mi][ni][v];
        if (ELU) val = (val > 0.f) ? val : expm1f(val);
        if (C_F32) ((float*)Cp)[(long)r*ldc + c] = val;
        else       ((bf16*)Cp)[(long)r*ldc + c] = (bf16)val;
      }
    }
  }
}

// ---------------- attention dots ----------------
__global__ void k_attdots(const bf16* __restrict__ h1, const float* __restrict__ att_s,
                          const float* __restrict__ att_d, float* __restrict__ a_src,
                          float* __restrict__ a_dst){
  int gid = blockIdx.x * blockDim.x + threadIdx.x;
  int row = gid >> 6, lane = gid & 63;
  if (row >= N_NODES) return;
  bf16x8 hv = *(const bf16x8*)(h1 + (long)row*HID + lane*8);
  float s1 = 0.f, s2 = 0.f;
  #pragma unroll
  for (int j=0;j<8;j++){
    float h = bf2f(hv[j]);
    s1 = fmaf(h, att_s[lane*8+j], s1);
    s2 = fmaf(h, att_d[lane*8+j], s2);
  }
  #pragma unroll
  for (int o=32;o>0;o>>=1){ s1 += __shfl_down(s1,o); s2 += __shfl_down(s2,o); }
  if (lane == 0){ a_src[row] = s1; a_dst[row] = s2; }
}

// ---------------- CSR build ----------------
__global__ void k_deg(const int* __restrict__ ei, int* __restrict__ deg){
  int e = blockIdx.x*256 + threadIdx.x;
  if (e >= N_EDGES) return;
  atomicAdd(&deg[ei[N_EDGES + e]], 1);
}

__global__ void k_scan(const int* __restrict__ deg, int* __restrict__ off, int* __restrict__ cur){
  const int n = M_PAD, T = 1024;
  int t = threadIdx.x;
  const int per = (n + T - 1) / T;
  int s0 = t*per, s1 = min(n, s0+per);
  int sum = 0;
  for (int i=s0;i<s1;i++) sum += deg[i];
  __shared__ int sd[1024];
  sd[t] = sum; __syncthreads();
  for (int o=1;o<T;o<<=1){
    int x = (t>=o) ? sd[t-o] : 0;
    __syncthreads();
    sd[t] += x;
    __syncthreads();
  }
  int run = sd[t] - sum;
  for (int i=s0;i<s1;i++){
    off[i] = run; cur[i] = run;
    run += deg[i];
  }
  if (s0 < n && s1 == n) off[n] = run;
}

// fill CSR and compute unnormalized p = exp(leaky(a_src+a_dst)) per slot.
__global__ void k_fill(const int* __restrict__ ei, int* __restrict__ cur,
                       int* __restrict__ csr_src, const float* __restrict__ a_s,
                       const float* __restrict__ a_d, float* __restrict__ p_e){
  int e = blockIdx.x*256 + threadIdx.x;
  if (e >= N_EDGES) return;
  int s = ei[e];
  int d = ei[N_EDGES + e];
  int pos = atomicAdd(&cur[d], 1);
  csr_src[pos] = s;
  float v = a_s[s] + a_d[d];
  v = (v > 0.f) ? v : 0.2f*v;
  p_e[pos] = __expf(v);
}

// ---------------- conv1 aggregation (no reductions) ----------------
__global__ __launch_bounds__(512) void k_agg1(
    const int* __restrict__ off, const int* __restrict__ csr_src,
    const float* __restrict__ p_edge,
    const bf16* __restrict__ h1, bf16* __restrict__ x1,
    float* __restrict__ s_node)
{
  const int i = blockIdx.x;
  const int t = threadIdx.x;
  const int start = off[i];
  const int deg = off[i+1] - start;
  __shared__ float p_sh[512];
  __shared__ int   s_sh[512];

  float acc = 0.f, ssum = 0.f;
  for (int base=0; base<deg; base+=512){
    int cnt = min(512, deg-base);
    if (t < cnt){
      p_sh[t] = p_edge[start+base+t];
      s_sh[t] = csr_src[start+base+t];
    }
    __syncthreads();
    for (int k=0;k<cnt;k++){
      float pk = p_sh[k];
      ssum += pk;
      acc = fmaf(pk, bf2f(h1[(long)s_sh[k]*HID + t]), acc);
    }
    __syncthreads();
  }
  float val = acc / (ssum + 1e-16f);
  val = (val > 0.f) ? val : expm1f(val);
  x1[(long)i*HID + t] = (bf16)val;
  if (t == 0) s_node[i] = ssum;
}

// ---------------- conv3 aggregate ----------------
__global__ void k_agg3(const int* __restrict__ off, const int* __restrict__ csr_src,
                       const float* __restrict__ p_edge, const float* __restrict__ s_node,
                       const float* __restrict__ x2, bf16* __restrict__ aggb)
{
  int i = blockIdx.x*8 + (threadIdx.x >> 5);
  int lane = threadIdx.x & 31;
  if (i >= M_PAD) return;
  float acc = 0.f;
  if (i < N_NODES){
    int s0 = off[i], d = off[i+1] - s0;
    for (int k=0;k<d;k++){
      int s = csr_src[s0+k];
      float pk = p_edge[s0+k];
      if (lane < LAT) acc = fmaf(pk, x2[(long)s*LAT + lane], acc);
    }
    acc *= 1.f/(s_node[i] + 1e-16f);
  }
  aggb[(long)i*32 + lane] = (bf16)((lane < LAT) ? acc : 0.f);
}

// ---------------- launch ----------------
extern "C" void kernel_launch(void* const* d_in, const int* in_sizes, int n_in,
                              void* d_out, int out_size, void* d_ws, size_t ws_size,
                              hipStream_t stream)
{
  const float* x     = (const float*)d_in[0];
  const int*   ei    = (const int*)d_in[1];
  const float* W1    = (const float*)d_in[2];
  const float* W2    = (const float*)d_in[3];
  const float* att_s = (const float*)d_in[4];
  const float* att_d = (const float*)d_in[5];

  float* out_x2 = (float*)d_out;                        // [N,30]
  float* out_x4 = (float*)d_out + (long)N_NODES*LAT;    // [N,3000] region

  // transient scratch inside the (not-yet-written) x4 region of d_out
  bf16* h1 = (bf16*)out_x4;                             // [M_PAD][HID]
  bf16* x1 = h1 + (long)M_PAD*HID;

  char* w = (char*)d_ws;
  bf16* W1T = (bf16*)w;  w += (long)HID*K1_PAD*2;
  bf16* W1P = (bf16*)w;  w += (long)N4_PAD*HID*2;
  bf16* W2T = (bf16*)w;  w += (long)128*HID*2;
  bf16* W2P = (bf16*)w;  w += (long)HID*32*2;
  bf16* x3  = (bf16*)w;  w += (long)M_PAD*HID*2;
  bf16* aggb= (bf16*)w;  w += (long)M_PAD*32*2;
  int* deg  = (int*)w;   w += (long)M_PAD*4;
  int* offs = (int*)w;   w += (long)(M_PAD+64)*4;
  int* cur  = (int*)w;   w += (long)M_PAD*4;
  int* csr  = (int*)w;   w += (long)N_EDGES*4;
  float* p_e = (float*)w; w += (long)N_EDGES*4;
  float* s_n = (float*)w; w += (long)M_PAD*4;
  float* a_s = (float*)w; w += (long)M_PAD*4;
  float* a_d = (float*)w; w += (long)M_PAD*4;

  // weight prep
  k_w1t<<<dim3((K1_PAD+255)/256, HID), 256, 0, stream>>>(W1, W1T);
  k_w1p<<<dim3((HID+255)/256, N4_PAD), 256, 0, stream>>>(W1, W1P);
  k_w2t<<<dim3(2, 128), 256, 0, stream>>>(W2, W2T);
  k_w2p<<<(HID*32+255)/256, 256, 0, stream>>>(W2, W2P);

  // CSR degree + offsets (independent of gemm1)
  hipMemsetAsync(deg, 0, (size_t)M_PAD*4, stream);
  k_deg<<<(N_EDGES+255)/256, 256, 0, stream>>>(ei, deg);
  k_scan<<<1, 1024, 0, stream>>>(deg, offs, cur);

  // h1 = x @ W1  (A-direct regs + counted vmcnt pipeline)
  gemm_a32r<<<(M_PAD/128)*(HID/128), 256, 0, stream>>>(x, W1T, h1);

  k_attdots<<<(N_NODES*64)/256, 256, 0, stream>>>(h1, att_s, att_d, a_s, a_d);

  // CSR fill + fused edge softmax numerator
  k_fill<<<(N_EDGES+255)/256, 256, 0, stream>>>(ei, cur, csr, a_s, a_d, p_e);

  k_agg1<<<N_NODES, 512, 0, stream>>>(offs, csr, p_e, h1, x1, s_n);

  // x2 = x1 @ W2 -> fp32 out
  gemm_glds<true,false><<<1*(M_PAD/128), 256, 0, stream>>>(
      x1, W2T, out_x2, HID, HID, HID/32, N_NODES, LAT, LAT, 1);

  // conv3: aggregate on 30-wide x2, then x3 = elu(aggb @ W2P^T)
  k_agg3<<<(M_PAD+7)/8, 256, 0, stream>>>(offs, csr, p_e, s_n, out_x2, aggb);
  gemm_glds<false,true><<<(HID/128)*(M_PAD/128), 256, 0, stream>>>(
      aggb, W2P, x3, 32, 32, 1, M_PAD, HID, HID, HID/128);

  // x4 = x3 @ W1^T -> fp32 out (overwrites h1/x1 scratch)
  gemm_glds<true,false><<<(N4_PAD/128)*(M_PAD/128), 256, 0, stream>>>(
      x3, W1P, out_x4, HID, HID, HID/32, N_NODES, IN_DIM, IN_DIM, N4_PAD/128);
}

// Round 5
// 1216.890 us; speedup vs baseline: 1.1792x; 1.1792x over previous
//
#include <hip/hip_runtime.h>

#define N_NODES 50000
#define IN_DIM  3000
#define HID     512
#define LAT     30
#define N_EDGES 800000
#define M_PAD   50048   // 391*128
#define K1_PAD  3008    // 94*32
#define N4_PAD  3072    // 24*128

typedef __bf16 bf16;
typedef unsigned int uint;
typedef __attribute__((ext_vector_type(4))) float f32x4;
typedef __attribute__((ext_vector_type(8))) bf16 bf16x8;

__device__ __forceinline__ float bf2f(bf16 b){ return (float)b; }

__device__ __forceinline__ void gl16(const void* g, void* l){
  __builtin_amdgcn_global_load_lds(
      (const __attribute__((address_space(1))) void*)g,
      (__attribute__((address_space(3))) void*)l, 16, 0, 0);
}

// bijective XCD-aware swizzle (m204)
__device__ __forceinline__ int xcd_swz(int orig, int nwg){
  int q = nwg >> 3, r = nwg & 7;
  int xcd = orig & 7, lid = orig >> 3;
  return (xcd < r ? xcd*(q+1) : r*(q+1) + (xcd-r)*q) + lid;
}

__device__ __forceinline__ bf16x8 cvt8v(f32x4 a, f32x4 b){
  bf16x8 r;
  r[0]=(bf16)a[0]; r[1]=(bf16)a[1]; r[2]=(bf16)a[2]; r[3]=(bf16)a[3];
  r[4]=(bf16)b[0]; r[5]=(bf16)b[1]; r[6]=(bf16)b[2]; r[7]=(bf16)b[3];
  return r;
}

// ---------------- weight prep ----------------
__global__ void k_w1t(const float* __restrict__ W1, bf16* __restrict__ W1T){
  int k = blockIdx.x*256 + threadIdx.x;
  int n = blockIdx.y;
  if (k >= K1_PAD) return;
  float v = (k < IN_DIM) ? W1[(long)k*HID + n] : 0.f;
  W1T[(long)n*K1_PAD + k] = (bf16)v;
}
__global__ void k_w1p(const float* __restrict__ W1, bf16* __restrict__ W1P){
  int k = blockIdx.x*256 + threadIdx.x;
  int n = blockIdx.y;
  if (k >= HID) return;
  float v = (n < IN_DIM) ? W1[(long)n*HID + k] : 0.f;
  W1P[(long)n*HID + k] = (bf16)v;
}
__global__ void k_w2t(const float* __restrict__ W2, bf16* __restrict__ W2T){
  int k = blockIdx.x*256 + threadIdx.x;
  int n = blockIdx.y;
  if (k >= HID) return;
  float v = (n < LAT) ? W2[(long)k*LAT + n] : 0.f;
  W2T[(long)n*HID + k] = (bf16)v;
}
__global__ void k_w2p(const float* __restrict__ W2, bf16* __restrict__ W2P){
  int t = blockIdx.x*256 + threadIdx.x;
  if (t >= HID*32) return;
  int n = t >> 5, k = t & 31;
  W2P[t] = (bf16)((k < LAT) ? W2[(long)n*LAT + k] : 0.f);
}

// ---- gemm1: h1 = (fp32 x) @ W1T^T ----
// m97 structure; A staged as fp32 via global_load_lds (16KB tile, XOR
// chunk-swizzle: linear LDS dest + inverse-swizzled global src + swizzled
// ds_read), cvt fp32->bf16 in-register after ds_read. B bf16 as before.
__global__ __launch_bounds__(256) void gemm_xw1(
    const float* __restrict__ X, const bf16* __restrict__ Bw, bf16* __restrict__ C)
{
  __shared__ float Af[128*32];    // 16 KB
  __shared__ bf16  Bl[128*32];    // 8 KB
  const int NBX = HID/128;        // 4
  const int tid  = threadIdx.x;
  const int lane = tid & 63;
  const int w    = tid >> 6;
  const int wm   = (w >> 1) * 64, wn = (w & 1) * 64;
  const int wgid = xcd_swz(blockIdx.x, gridDim.x);
  const int col0 = (wgid % NBX) * 128, row0 = (wgid / NBX) * 128;

  f32x4 acc[4][4];
  #pragma unroll
  for (int mi=0;mi<4;mi++)
    #pragma unroll
    for (int ni=0;ni<4;ni++)
      acc[mi][ni] = (f32x4){0.f,0.f,0.f,0.f};

  // A staging: call i covers LDS rows i*32..i*32+31; thread -> (row, chunk)
  const int ar  = tid >> 3;               // row within call (0..31)
  const int apc = tid & 7;                // physical 16B chunk
  const int ac4 = (apc ^ (ar & 7)) * 4;   // logical element offset (swizzled)
  int aoff[4];
  #pragma unroll
  for (int i=0;i<4;i++)
    aoff[i] = min(row0 + i*32 + ar, N_NODES-1) * IN_DIM;

  // B staging (linear)
  const int sr = tid >> 2;
  const int sc = (tid & 3) * 16;
  const char* gB = (const char*)(Bw + (long)(col0 + sr) * K1_PAD) + sc;
  const long bstep = (long)64 * K1_PAD * 2;
  float* lA = Af + tid*4;                 // byte tid*16; +i*1024 floats per call
  char*  lB = (char*)Bl + sr*64 + sc;

  for (int ks = 0; ks < 94; ks++){
    int kcl = min(ks*32 + ac4, IN_DIM-4);
    #pragma unroll
    for (int i=0;i<4;i++)
      gl16(X + aoff[i] + kcl, lA + i*1024);
    gl16(gB + (long)ks*64,         lB);
    gl16(gB + (long)ks*64 + bstep, lB + 64*64);
    __syncthreads();

    const int g2 = (lane >> 4) * 2;
    bf16x8 af[4], bfr[4];
    #pragma unroll
    for (int mi=0;mi<4;mi++){
      int row = wm + mi*16 + (lane & 15);
      int rx  = row & 7;
      f32x4 f0 = *(const f32x4*)&Af[row*32 + ((g2    ) ^ rx)*4];
      f32x4 f1 = *(const f32x4*)&Af[row*32 + ((g2 + 1) ^ rx)*4];
      af[mi] = cvt8v(f0, f1);
    }
    #pragma unroll
    for (int ni=0;ni<4;ni++)
      bfr[ni] = *(const bf16x8*)&Bl[(wn + ni*16 + (lane & 15))*32 + (lane>>4)*8];
    #pragma unroll
    for (int mi=0;mi<4;mi++)
      #pragma unroll
      for (int ni=0;ni<4;ni++)
        acc[mi][ni] = __builtin_amdgcn_mfma_f32_16x16x32_bf16(af[mi], bfr[ni], acc[mi][ni], 0, 0, 0);
    __syncthreads();
  }

  const int crb  = (lane >> 4) * 4;
  const int ccol = lane & 15;
  #pragma unroll
  for (int mi=0;mi<4;mi++){
    #pragma unroll
    for (int v=0;v<4;v++){
      int r = row0 + wm + mi*16 + crb + v;
      if (r >= N_NODES) continue;
      #pragma unroll
      for (int ni=0;ni<4;ni++){
        int cc = col0 + wn + ni*16 + ccol;
        C[(long)r*HID + cc] = (bf16)acc[mi][ni][v];
      }
    }
  }
}

// ---------------- GEMM (m97 structure): C = A * B^T, flat grid + swizzle ----
template<bool C_F32, bool ELU>
__global__ __launch_bounds__(256) void gemm_glds(
    const bf16* __restrict__ A, const bf16* __restrict__ B, void* __restrict__ Cp,
    int lda, int ldb, int Ksteps, int Mvalid, int Nvalid, int ldc, int NBX)
{
  __shared__ bf16 Alds[128*32];
  __shared__ bf16 Blds[128*32];
  const int tid  = threadIdx.x;
  const int lane = tid & 63;
  const int w    = tid >> 6;
  const int wm   = (w >> 1) * 64, wn = (w & 1) * 64;
  const int wgid = xcd_swz(blockIdx.x, gridDim.x);
  const int col0 = (wgid % NBX) * 128, row0 = (wgid / NBX) * 128;

  f32x4 acc[4][4];
  #pragma unroll
  for (int mi=0;mi<4;mi++)
    #pragma unroll
    for (int ni=0;ni<4;ni++)
      acc[mi][ni] = (f32x4){0.f,0.f,0.f,0.f};

  const int sr = tid >> 2;
  const int sc = (tid & 3) * 16;

  const char* ga = (const char*)(A + (long)(row0 + sr) * lda) + sc;
  const char* gb = (const char*)(B + (long)(col0 + sr) * ldb) + sc;
  char* la = (char*)Alds + sr*64 + sc;
  char* lb = (char*)Blds + sr*64 + sc;
  const long astep = (long)64 * lda * 2;
  const long bstep = (long)64 * ldb * 2;

  for (int ks = 0; ks < Ksteps; ks++){
    const long ko = (long)ks * 64;
    gl16(ga + ko,         la);
    gl16(ga + ko + astep, la + 64*64);
    gl16(gb + ko,         lb);
    gl16(gb + ko + bstep, lb + 64*64);
    __syncthreads();

    bf16x8 af[4], bfr[4];
    #pragma unroll
    for (int mi=0;mi<4;mi++)
      af[mi] = *(const bf16x8*)&Alds[(wm + mi*16 + (lane & 15))*32 + (lane>>4)*8];
    #pragma unroll
    for (int ni=0;ni<4;ni++)
      bfr[ni] = *(const bf16x8*)&Blds[(wn + ni*16 + (lane & 15))*32 + (lane>>4)*8];
    #pragma unroll
    for (int mi=0;mi<4;mi++)
      #pragma unroll
      for (int ni=0;ni<4;ni++)
        acc[mi][ni] = __builtin_amdgcn_mfma_f32_16x16x32_bf16(af[mi], bfr[ni], acc[mi][ni], 0, 0, 0);
    __syncthreads();
  }

  const int crb  = (lane >> 4) * 4;
  const int ccol = lane & 15;
  #pragma unroll
  for (int mi=0;mi<4;mi++){
    #pragma unroll
    for (int v=0;v<4;v++){
      int r = row0 + wm + mi*16 + crb + v;
      if (r >= Mvalid) continue;
      #pragma unroll
      for (int ni=0;ni<4;ni++){
        int c = col0 + wn + ni*16 + ccol;
        if (c >= Nvalid) continue;
        float val = acc[mi][ni][v];
        if (ELU) val = (val > 0.f) ? val : expm1f(val);
        if (C_F32) ((float*)Cp)[(long)r*ldc + c] = val;
        else       ((bf16*)Cp)[(long)r*ldc + c] = (bf16)val;
      }
    }
  }
}

// ---------------- attention dots ----------------
__global__ void k_attdots(const bf16* __restrict__ h1, const float* __restrict__ att_s,
                          const float* __restrict__ att_d, float* __restrict__ a_src,
                          float* __restrict__ a_dst){
  int gid = blockIdx.x * blockDim.x + threadIdx.x;
  int row = gid >> 6, lane = gid & 63;
  if (row >= N_NODES) return;
  bf16x8 hv = *(const bf16x8*)(h1 + (long)row*HID + lane*8);
  float s1 = 0.f, s2 = 0.f;
  #pragma unroll
  for (int j=0;j<8;j++){
    float h = bf2f(hv[j]);
    s1 = fmaf(h, att_s[lane*8+j], s1);
    s2 = fmaf(h, att_d[lane*8+j], s2);
  }
  #pragma unroll
  for (int o=32;o>0;o>>=1){ s1 += __shfl_down(s1,o); s2 += __shfl_down(s2,o); }
  if (lane == 0){ a_src[row] = s1; a_dst[row] = s2; }
}

// ---------------- CSR build ----------------
__global__ void k_deg(const int* __restrict__ ei, int* __restrict__ deg){
  int e = blockIdx.x*256 + threadIdx.x;
  if (e >= N_EDGES) return;
  atomicAdd(&deg[ei[N_EDGES + e]], 1);
}

__global__ void k_scan(const int* __restrict__ deg, int* __restrict__ off, int* __restrict__ cur){
  const int n = M_PAD, T = 1024;
  int t = threadIdx.x;
  const int per = (n + T - 1) / T;
  int s0 = t*per, s1 = min(n, s0+per);
  int sum = 0;
  for (int i=s0;i<s1;i++) sum += deg[i];
  __shared__ int sd[1024];
  sd[t] = sum; __syncthreads();
  for (int o=1;o<T;o<<=1){
    int x = (t>=o) ? sd[t-o] : 0;
    __syncthreads();
    sd[t] += x;
    __syncthreads();
  }
  int run = sd[t] - sum;
  for (int i=s0;i<s1;i++){
    off[i] = run; cur[i] = run;
    run += deg[i];
  }
  if (s0 < n && s1 == n) off[n] = run;
}

// fill CSR and compute unnormalized p = exp(leaky(a_src+a_dst)) per slot.
__global__ void k_fill(const int* __restrict__ ei, int* __restrict__ cur,
                       int* __restrict__ csr_src, const float* __restrict__ a_s,
                       const float* __restrict__ a_d, float* __restrict__ p_e){
  int e = blockIdx.x*256 + threadIdx.x;
  if (e >= N_EDGES) return;
  int s = ei[e];
  int d = ei[N_EDGES + e];
  int pos = atomicAdd(&cur[d], 1);
  csr_src[pos] = s;
  float v = a_s[s] + a_d[d];
  v = (v > 0.f) ? v : 0.2f*v;
  p_e[pos] = __expf(v);
}

// ---------------- conv1 aggregation (no reductions) ----------------
__global__ __launch_bounds__(512) void k_agg1(
    const int* __restrict__ off, const int* __restrict__ csr_src,
    const float* __restrict__ p_edge,
    const bf16* __restrict__ h1, bf16* __restrict__ x1,
    float* __restrict__ s_node)
{
  const int i = blockIdx.x;
  const int t = threadIdx.x;
  const int start = off[i];
  const int deg = off[i+1] - start;
  __shared__ float p_sh[512];
  __shared__ int   s_sh[512];

  float acc = 0.f, ssum = 0.f;
  for (int base=0; base<deg; base+=512){
    int cnt = min(512, deg-base);
    if (t < cnt){
      p_sh[t] = p_edge[start+base+t];
      s_sh[t] = csr_src[start+base+t];
    }
    __syncthreads();
    for (int k=0;k<cnt;k++){
      float pk = p_sh[k];
      ssum += pk;
      acc = fmaf(pk, bf2f(h1[(long)s_sh[k]*HID + t]), acc);
    }
    __syncthreads();
  }
  float val = acc / (ssum + 1e-16f);
  val = (val > 0.f) ? val : expm1f(val);
  x1[(long)i*HID + t] = (bf16)val;
  if (t == 0) s_node[i] = ssum;
}

// ---------------- conv3 aggregate ----------------
__global__ void k_agg3(const int* __restrict__ off, const int* __restrict__ csr_src,
                       const float* __restrict__ p_edge, const float* __restrict__ s_node,
                       const float* __restrict__ x2, bf16* __restrict__ aggb)
{
  int i = blockIdx.x*8 + (threadIdx.x >> 5);
  int lane = threadIdx.x & 31;
  if (i >= M_PAD) return;
  float acc = 0.f;
  if (i < N_NODES){
    int s0 = off[i], d = off[i+1] - s0;
    for (int k=0;k<d;k++){
      int s = csr_src[s0+k];
      float pk = p_edge[s0+k];
      if (lane < LAT) acc = fmaf(pk, x2[(long)s*LAT + lane], acc);
    }
    acc *= 1.f/(s_node[i] + 1e-16f);
  }
  aggb[(long)i*32 + lane] = (bf16)((lane < LAT) ? acc : 0.f);
}

// ---------------- launch ----------------
extern "C" void kernel_launch(void* const* d_in, const int* in_sizes, int n_in,
                              void* d_out, int out_size, void* d_ws, size_t ws_size,
                              hipStream_t stream)
{
  const float* x     = (const float*)d_in[0];
  const int*   ei    = (const int*)d_in[1];
  const float* W1    = (const float*)d_in[2];
  const float* W2    = (const float*)d_in[3];
  const float* att_s = (const float*)d_in[4];
  const float* att_d = (const float*)d_in[5];

  float* out_x2 = (float*)d_out;                        // [N,30]
  float* out_x4 = (float*)d_out + (long)N_NODES*LAT;    // [N,3000] region

  // transient scratch inside the (not-yet-written) x4 region of d_out
  bf16* h1 = (bf16*)out_x4;                             // [M_PAD][HID]
  bf16* x1 = h1 + (long)M_PAD*HID;

  char* w = (char*)d_ws;
  bf16* W1T = (bf16*)w;  w += (long)HID*K1_PAD*2;
  bf16* W1P = (bf16*)w;  w += (long)N4_PAD*HID*2;
  bf16* W2T = (bf16*)w;  w += (long)128*HID*2;
  bf16* W2P = (bf16*)w;  w += (long)HID*32*2;
  bf16* x3  = (bf16*)w;  w += (long)M_PAD*HID*2;
  bf16* aggb= (bf16*)w;  w += (long)M_PAD*32*2;
  int* deg  = (int*)w;   w += (long)M_PAD*4;
  int* offs = (int*)w;   w += (long)(M_PAD+64)*4;
  int* cur  = (int*)w;   w += (long)M_PAD*4;
  int* csr  = (int*)w;   w += (long)N_EDGES*4;
  float* p_e = (float*)w; w += (long)N_EDGES*4;
  float* s_n = (float*)w; w += (long)M_PAD*4;
  float* a_s = (float*)w; w += (long)M_PAD*4;
  float* a_d = (float*)w; w += (long)M_PAD*4;

  // weight prep
  k_w1t<<<dim3((K1_PAD+255)/256, HID), 256, 0, stream>>>(W1, W1T);
  k_w1p<<<dim3((HID+255)/256, N4_PAD), 256, 0, stream>>>(W1, W1P);
  k_w2t<<<dim3(2, 128), 256, 0, stream>>>(W2, W2T);
  k_w2p<<<(HID*32+255)/256, 256, 0, stream>>>(W2, W2P);

  // CSR degree + offsets (independent of gemm1)
  hipMemsetAsync(deg, 0, (size_t)M_PAD*4, stream);
  k_deg<<<(N_EDGES+255)/256, 256, 0, stream>>>(ei, deg);
  k_scan<<<1, 1024, 0, stream>>>(deg, offs, cur);

  // h1 = x @ W1  (fp32-A-in-LDS, m97 structure)
  gemm_xw1<<<(M_PAD/128)*(HID/128), 256, 0, stream>>>(x, W1T, h1);

  k_attdots<<<(N_NODES*64)/256, 256, 0, stream>>>(h1, att_s, att_d, a_s, a_d);

  // CSR fill + fused edge softmax numerator
  k_fill<<<(N_EDGES+255)/256, 256, 0, stream>>>(ei, cur, csr, a_s, a_d, p_e);

  k_agg1<<<N_NODES, 512, 0, stream>>>(offs, csr, p_e, h1, x1, s_n);

  // x2 = x1 @ W2 -> fp32 out
  gemm_glds<true,false><<<1*(M_PAD/128), 256, 0, stream>>>(
      x1, W2T, out_x2, HID, HID, HID/32, N_NODES, LAT, LAT, 1);

  // conv3: aggregate on 30-wide x2, then x3 = elu(aggb @ W2P^T)
  k_agg3<<<(M_PAD+7)/8, 256, 0, stream>>>(offs, csr, p_e, s_n, out_x2, aggb);
  gemm_glds<false,true><<<(HID/128)*(M_PAD/128), 256, 0, stream>>>(
      aggb, W2P, x3, 32, 32, 1, M_PAD, HID, HID, HID/128);

  // x4 = x3 @ W1^T -> fp32 out (overwrites h1/x1 scratch)
  gemm_glds<true,false><<<(N4_PAD/128)*(M_PAD/128), 256, 0, stream>>>(
      x3, W1P, out_x4, HID, HID, HID/32, N_NODES, IN_DIM, IN_DIM, N4_PAD/128);
}